// Round 16
// baseline (250.672 us; speedup 1.0000x reference)
//
#include <hip/hip_runtime.h>
#include <hip/hip_bf16.h>

#define CCH 64      // channels
#define NPIX 4096   // 64*64 pooled points
#define LOG2E 1.4426950408889634f
#define REPS 4      // attn attribution: 4 identical passes in ONE dispatch

typedef __attribute__((ext_vector_type(8))) short short8;   // 8 bf16 (4 VGPRs)
typedef __attribute__((ext_vector_type(16))) float f32x16;  // MFMA 32x32 accumulator

union U4S8 { uint4 u; short8 s; };

__device__ inline uint32_t pk2bf(float lo, float hi) {
    __hip_bfloat162 h = __float22bfloat162_rn(make_float2(lo, hi));
    return *reinterpret_cast<uint32_t*>(&h);
}

// ---------------------------------------------------------------------------
// Kernel 1: fused avg-pool 4x4 + 1x1 convs via MFMA. (unchanged from R13;
// Q pre-scaled by log2e). Measured ~27.7 us — near read floor.
// ---------------------------------------------------------------------------
__global__ __launch_bounds__(256, 4) void pool_conv_kernel(
    const float* __restrict__ x,
    const float* __restrict__ Wq, const float* __restrict__ bq,
    const float* __restrict__ Wk, const float* __restrict__ bk,
    const float* __restrict__ Wv, const float* __restrict__ bv,
    __hip_bfloat16* __restrict__ Qo, __hip_bfloat16* __restrict__ Ko,
    __hip_bfloat16* __restrict__ VPo)
{
    const int blk  = blockIdx.x;
    const int b    = blk >> 7;
    const int prow = (blk >> 1) & 63;    // pooled row
    const int half = blk & 1;            // pooled col half (32 cols)
    const int t    = threadIdx.x;
    const int lane = t & 63;
    const int w    = t >> 6;
    const int l31  = lane & 31;
    const int hi   = lane >> 5;

    __shared__ __align__(16) __hip_bfloat16 xdt[32][72];    // [pt][ch]
    __shared__ __align__(16) __hip_bfloat16 otile[80][36];  // [oc][pt]
    __shared__ float sbias[96];

    if (t < 96) {
        float v = 0.f;
        if (t < 8)       v = bq[t];
        else if (t < 16) v = bk[t-8];
        else if (t < 80) v = bv[t-16];
        sbias[t] = v;
    }

    const float* xbase = x + (((size_t)(b*CCH))*256 + (size_t)(prow*4 + hi))*256
                           + half*128 + l31*4;
    #pragma unroll
    for (int cc = 0; cc < 16; ++cc) {
        const int c = w*16 + cc;
        const float* xp = xbase + (size_t)c*65536;
        float4 a0 = *(const float4*)(xp);
        float4 a1 = *(const float4*)(xp + 512);    // +2 rows
        float s = (a0.x+a0.y+a0.z+a0.w) + (a1.x+a1.y+a1.z+a1.w);
        s += __shfl_xor(s, 32);                    // combine row pairs
        if (hi == 0) xdt[l31][c] = __float2bfloat16(s * 0.0625f);
    }

    const int  oct  = w;
    const bool busy = (w < 3);
    short8 wf[4];
    if (busy) {
        const int row = oct*32 + l31;
        const float* wr = nullptr;
        if (row < 8)       wr = Wq + row*CCH;
        else if (row < 16) wr = Wk + (row-8)*CCH;
        else if (row < 80) wr = Wv + (row-16)*CCH;
        #pragma unroll
        for (int kt = 0; kt < 4; ++kt) {
            U4S8 f;
            if (wr) {
                const int c0 = kt*16 + hi*8;
                float4 a = *(const float4*)(wr + c0);
                float4 d = *(const float4*)(wr + c0 + 4);
                f.u.x = pk2bf(a.x, a.y); f.u.y = pk2bf(a.z, a.w);
                f.u.z = pk2bf(d.x, d.y); f.u.w = pk2bf(d.z, d.w);
            } else {
                f.u = make_uint4(0,0,0,0);
            }
            wf[kt] = f.s;
        }
    }

    __syncthreads();

    if (busy) {
        short8 xf[4];
        #pragma unroll
        for (int kt = 0; kt < 4; ++kt)
            xf[kt] = *(const short8*)&xdt[l31][kt*16 + hi*8];

        f32x16 acc;
        #pragma unroll
        for (int r = 0; r < 16; ++r) acc[r] = 0.f;
        #pragma unroll
        for (int kt = 0; kt < 4; ++kt)
            acc = __builtin_amdgcn_mfma_f32_32x32x16_bf16(wf[kt], xf[kt], acc, 0, 0, 0);

        #pragma unroll
        for (int r = 0; r < 16; ++r) {
            const int row = (r&3) + 8*(r>>2) + 4*hi;
            const int oc  = oct*32 + row;
            if (oc < 80) {
                float v = acc[r] + sbias[oc];
                if (oc < 8) v *= LOG2E;   // Q pre-scale
                otile[oc][l31] = __float2bfloat16(v);
            }
        }
    }
    __syncthreads();

    const int i0 = prow*64 + half*32;
    if (t < 64) {
        const int p = t & 31;
        const int oc0 = (t < 32) ? 0 : 8;
        unsigned short v[8];
        #pragma unroll
        for (int j = 0; j < 8; ++j)
            v[j] = *reinterpret_cast<const unsigned short*>(&otile[oc0 + j][p]);
        uint4 q;
        q.x = (uint32_t)v[0] | ((uint32_t)v[1] << 16);
        q.y = (uint32_t)v[2] | ((uint32_t)v[3] << 16);
        q.z = (uint32_t)v[4] | ((uint32_t)v[5] << 16);
        q.w = (uint32_t)v[6] | ((uint32_t)v[7] << 16);
        __hip_bfloat16* dst = (t < 32) ? Qo : Ko;
        *(uint4*)(dst + ((size_t)b*NPIX + i0 + p)*8) = q;
    }
    {
        const int chg = i0 >> 5;
        __hip_bfloat16* vdst = VPo + ((size_t)b*512 + (size_t)chg*4)*512;
        const int f   = t >> 6;
        const int s1  = f >> 1;
        const int ct  = f & 1;
        const int l   = t & 63;
        const int c31 = l & 31;
        const int h2  = l >> 5;
        const int row = 16 + ct*32 + c31;
        const int pt0 = s1*16 + h2*4;
        uint2 a0 = *(const uint2*)&otile[row][pt0];         // j = 0..3
        uint2 a1 = *(const uint2*)&otile[row][pt0 + 8];     // j = 4..7
        *(uint4*)(vdst + t*8) = make_uint4(a0.x, a0.y, a1.x, a1.y);
    }
}

// ---------------------------------------------------------------------------
// Kernel 2: flash attention, SOFTWARE-PIPELINED inner loop:
//   - 2-chunk unroll, A/B register buffer rotation (two independent
//     S->exp2->PV chains per iteration for the scheduler to interleave)
//   - prefetch issued ~1.5 chunks ahead of use
//   - pointer-bump addressing; VP's 4 frag loads share one base with
//     1KB/2KB/3KB immediate offsets
// REPS=4 identical passes inside ONE dispatch (attribution: this dispatch
// tops the rocprof table next round -> real counters for attn).
// ---------------------------------------------------------------------------
__global__ __launch_bounds__(256, 4) void attn_kernel(
    const __hip_bfloat16* __restrict__ Q, const __hip_bfloat16* __restrict__ K,
    const __hip_bfloat16* __restrict__ VP, float* __restrict__ OS)
{
    const int bb   = blockIdx.x;
    const int b    = bb & 7;          // XCD-locality: batch per XCD
    const int qg   = bb >> 3;         // 0..127
    const int i0   = qg * 32;
    const int t    = threadIdx.x;
    const int lane = t & 63;
    const int kvq  = t >> 6;          // wave = kv quarter
    const int l31  = lane & 31;
    const int hi   = lane >> 5;

    __shared__ float tiles[4][64][33];
    __shared__ float ml[4][32];
    __shared__ float ils[32];

    U4S8 qf;
    if (hi == 0) qf.u = *(const uint4*)(Q + ((size_t)b*NPIX + i0 + l31)*8);
    else         qf.u = make_uint4(0,0,0,0);

    const __hip_bfloat16* Kb  = K  + (size_t)b*NPIX*8;
    const __hip_bfloat16* VPb = VP + (size_t)b*512*512;   // 512 frags x 512 bf16

    f32x16 zacc;
    #pragma unroll
    for (int r = 0; r < 16; ++r) zacc[r] = 0.f;

    #pragma unroll 1
    for (int rep = 0; rep < REPS; ++rep) {
        __syncthreads();   // previous rep's tile readers done

        f32x16 acc0, acc1;
        #pragma unroll
        for (int r = 0; r < 16; ++r) { acc0[r] = 0.f; acc1[r] = 0.f; }
        float l = 0.f;

        // per-chunk strides: K +256 elems (512B), VP +2048 elems (4KB)
        const __hip_bfloat16* Kp = Kb  + (size_t)(kvq*1024 + l31)*8;
        const __hip_bfloat16* Vp = VPb + (size_t)(kvq*32)*2048 + (size_t)lane*8;

        U4S8 kA, kB, vA0, vA1, vA2, vA3, vB0, vB1, vB2, vB3;
        // prologue: chunks 0,1 of this quarter
        if (hi == 0) kA.u = *(const uint4*)Kp; else kA.u = make_uint4(0,0,0,0);
        vA0.u = *(const uint4*)(Vp);
        vA1.u = *(const uint4*)(Vp + 512);
        vA2.u = *(const uint4*)(Vp + 1024);
        vA3.u = *(const uint4*)(Vp + 1536);
        Kp += 256; Vp += 2048;
        if (hi == 0) kB.u = *(const uint4*)Kp; else kB.u = make_uint4(0,0,0,0);
        vB0.u = *(const uint4*)(Vp);
        vB1.u = *(const uint4*)(Vp + 512);
        vB2.u = *(const uint4*)(Vp + 1024);
        vB3.u = *(const uint4*)(Vp + 1536);
        Kp += 256; Vp += 2048;

        #pragma unroll 1
        for (int it = 0; it < 16; ++it) {
            // ======== chunk 2*it (A buffers) ========
            {
                f32x16 s = __builtin_amdgcn_mfma_f32_32x32x16_bf16(kA.s, qf.s, zacc, 0, 0, 0);
                // kA consumed -> prefetch chunk 2*it+2
                if (hi == 0) kA.u = *(const uint4*)Kp; else kA.u = make_uint4(0,0,0,0);
                Kp += 256;

                U4S8 pb0, pb1;
                float e0, e1;
                e0 = __builtin_exp2f(s[0]);  e1 = __builtin_exp2f(s[1]);
                l += e0 + e1;  pb0.u.x = pk2bf(e0, e1);
                e0 = __builtin_exp2f(s[2]);  e1 = __builtin_exp2f(s[3]);
                l += e0 + e1;  pb0.u.y = pk2bf(e0, e1);
                e0 = __builtin_exp2f(s[4]);  e1 = __builtin_exp2f(s[5]);
                l += e0 + e1;  pb0.u.z = pk2bf(e0, e1);
                e0 = __builtin_exp2f(s[6]);  e1 = __builtin_exp2f(s[7]);
                l += e0 + e1;  pb0.u.w = pk2bf(e0, e1);
                e0 = __builtin_exp2f(s[8]);  e1 = __builtin_exp2f(s[9]);
                l += e0 + e1;  pb1.u.x = pk2bf(e0, e1);
                e0 = __builtin_exp2f(s[10]); e1 = __builtin_exp2f(s[11]);
                l += e0 + e1;  pb1.u.y = pk2bf(e0, e1);
                e0 = __builtin_exp2f(s[12]); e1 = __builtin_exp2f(s[13]);
                l += e0 + e1;  pb1.u.z = pk2bf(e0, e1);
                e0 = __builtin_exp2f(s[14]); e1 = __builtin_exp2f(s[15]);
                l += e0 + e1;  pb1.u.w = pk2bf(e0, e1);

                acc0 = __builtin_amdgcn_mfma_f32_32x32x16_bf16(vA0.s, pb0.s, acc0, 0, 0, 0);
                acc1 = __builtin_amdgcn_mfma_f32_32x32x16_bf16(vA1.s, pb0.s, acc1, 0, 0, 0);
                acc0 = __builtin_amdgcn_mfma_f32_32x32x16_bf16(vA2.s, pb1.s, acc0, 0, 0, 0);
                acc1 = __builtin_amdgcn_mfma_f32_32x32x16_bf16(vA3.s, pb1.s, acc1, 0, 0, 0);
                // vA consumed -> prefetch chunk 2*it+2
                vA0.u = *(const uint4*)(Vp);
                vA1.u = *(const uint4*)(Vp + 512);
                vA2.u = *(const uint4*)(Vp + 1024);
                vA3.u = *(const uint4*)(Vp + 1536);
                Vp += 2048;
            }
            // ======== chunk 2*it+1 (B buffers) ========
            {
                f32x16 s = __builtin_amdgcn_mfma_f32_32x32x16_bf16(kB.s, qf.s, zacc, 0, 0, 0);
                if (hi == 0) kB.u = *(const uint4*)Kp; else kB.u = make_uint4(0,0,0,0);
                Kp += 256;

                U4S8 pb0, pb1;
                float e0, e1;
                e0 = __builtin_exp2f(s[0]);  e1 = __builtin_exp2f(s[1]);
                l += e0 + e1;  pb0.u.x = pk2bf(e0, e1);
                e0 = __builtin_exp2f(s[2]);  e1 = __builtin_exp2f(s[3]);
                l += e0 + e1;  pb0.u.y = pk2bf(e0, e1);
                e0 = __builtin_exp2f(s[4]);  e1 = __builtin_exp2f(s[5]);
                l += e0 + e1;  pb0.u.z = pk2bf(e0, e1);
                e0 = __builtin_exp2f(s[6]);  e1 = __builtin_exp2f(s[7]);
                l += e0 + e1;  pb0.u.w = pk2bf(e0, e1);
                e0 = __builtin_exp2f(s[8]);  e1 = __builtin_exp2f(s[9]);
                l += e0 + e1;  pb1.u.x = pk2bf(e0, e1);
                e0 = __builtin_exp2f(s[10]); e1 = __builtin_exp2f(s[11]);
                l += e0 + e1;  pb1.u.y = pk2bf(e0, e1);
                e0 = __builtin_exp2f(s[12]); e1 = __builtin_exp2f(s[13]);
                l += e0 + e1;  pb1.u.z = pk2bf(e0, e1);
                e0 = __builtin_exp2f(s[14]); e1 = __builtin_exp2f(s[15]);
                l += e0 + e1;  pb1.u.w = pk2bf(e0, e1);

                acc0 = __builtin_amdgcn_mfma_f32_32x32x16_bf16(vB0.s, pb0.s, acc0, 0, 0, 0);
                acc1 = __builtin_amdgcn_mfma_f32_32x32x16_bf16(vB1.s, pb0.s, acc1, 0, 0, 0);
                acc0 = __builtin_amdgcn_mfma_f32_32x32x16_bf16(vB2.s, pb1.s, acc0, 0, 0, 0);
                acc1 = __builtin_amdgcn_mfma_f32_32x32x16_bf16(vB3.s, pb1.s, acc1, 0, 0, 0);
                vB0.u = *(const uint4*)(Vp);
                vB1.u = *(const uint4*)(Vp + 512);
                vB2.u = *(const uint4*)(Vp + 1024);
                vB3.u = *(const uint4*)(Vp + 1536);
                Vp += 2048;
            }
        }
        // (last-iteration prefetches read past the quarter: stays inside d_ws,
        // values unused — same as previous rounds.)

        l += __shfl_xor(l, 32);   // partner half holds other 16 kv per chunk

        #pragma unroll
        for (int r = 0; r < 16; ++r) {
            const int cr = (r&3) + 8*(r>>2) + 4*hi;
            tiles[kvq][cr]     [l31] = acc0[r];
            tiles[kvq][cr + 32][l31] = acc1[r];
        }
        if (hi == 0) ml[kvq][l31] = l;
        __syncthreads();

        if (t < 32) ils[t] = 1.f / (ml[0][t] + ml[1][t] + ml[2][t] + ml[3][t]);
        __syncthreads();

        float* outp = OS + (size_t)b*CCH*NPIX + i0;
        const int c  = t >> 2;
        const int q8 = (t & 3) * 8;
        float o[8];
        #pragma unroll
        for (int j = 0; j < 8; ++j) {
            const int q = q8 + j;
            float v = tiles[0][c][q] + tiles[1][c][q] + tiles[2][c][q] + tiles[3][c][q];
            o[j] = v * ils[q];
        }
        *(float4*)(outp + (size_t)c*NPIX + q8)     = make_float4(o[0], o[1], o[2], o[3]);
        *(float4*)(outp + (size_t)c*NPIX + q8 + 4) = make_float4(o[4], o[5], o[6], o[7]);
    }
}

// ---------------------------------------------------------------------------
// Kernel 3: bilinear x4 upsample + residual (unchanged; measured ~42.7 us,
// at its memory floor).
// ---------------------------------------------------------------------------
__global__ __launch_bounds__(256) void upsample_add_kernel(
    const float* __restrict__ OS, const float* __restrict__ x,
    const float* __restrict__ gamma, float* __restrict__ out)
{
    const size_t qidx = (size_t)blockIdx.x * 256 + threadIdx.x;  // float4 index
    const size_t idx  = qidx * 4;
    const float g = gamma[0];
    const int w4 = (int)(idx & 255);
    const int h  = (int)((idx >> 8) & 255);
    const size_t bc = idx >> 16;

    const float scale = 63.0f / 255.0f;
    float fh = h * scale; int h0 = (int)fh; float fy = fh - (float)h0; int h1 = min(h0+1, 63);

    const float* r0 = OS + bc * (size_t)NPIX + h0*64;
    const float* r1 = OS + bc * (size_t)NPIX + h1*64;
    float4 xi = *(const float4*)(x + idx);

    float o[4];
    #pragma unroll
    for (int j = 0; j < 4; ++j) {
        const int w = w4 + j;
        float fw = w * scale; int w0 = (int)fw; float fx = fw - (float)w0; int w1 = min(w0+1, 63);
        float a0 = r0[w0], a1 = r0[w1], b0 = r1[w0], b1 = r1[w1];
        float vt = a0 + (a1 - a0) * fx;
        float vb = b0 + (b1 - b0) * fx;
        o[j] = vt + (vb - vt) * fy;
    }
    float4 ov;
    ov.x = g*o[0] + xi.x; ov.y = g*o[1] + xi.y;
    ov.z = g*o[2] + xi.z; ov.w = g*o[3] + xi.w;
    *(float4*)(out + idx) = ov;
}

// ---------------------------------------------------------------------------
extern "C" void kernel_launch(void* const* d_in, const int* in_sizes, int n_in,
                              void* d_out, int out_size, void* d_ws, size_t ws_size,
                              hipStream_t stream) {
    const float* x     = (const float*)d_in[0];
    const float* Wq    = (const float*)d_in[1];
    const float* bq    = (const float*)d_in[2];
    const float* Wk    = (const float*)d_in[3];
    const float* bk    = (const float*)d_in[4];
    const float* Wv    = (const float*)d_in[5];
    const float* bv    = (const float*)d_in[6];
    const float* gamma = (const float*)d_in[7];
    float* out = (float*)d_out;

    char* ws = (char*)d_ws;
    __hip_bfloat16* Qb = (__hip_bfloat16*)(ws);                      // 512 KB
    __hip_bfloat16* Kb = (__hip_bfloat16*)(ws + (size_t)( 512<<10)); // 512 KB
    __hip_bfloat16* VP = (__hip_bfloat16*)(ws + (size_t)(1024<<10)); // 4 MB packed
    float*          OS = (float*)         (ws + (size_t)(5120<<10)); // 8 MB

    pool_conv_kernel<<<1024, 256, 0, stream>>>(x, Wq, bq, Wk, bk, Wv, bv, Qb, Kb, VP);
    // attn runs REPS=4 passes internally (single dispatch -> visible in rocprof)
    attn_kernel<<<1024, 256, 0, stream>>>(Qb, Kb, VP, OS);
    const size_t total4 = (size_t)8 * 64 * 256 * 256 / 4;
    upsample_add_kernel<<<(int)(total4 / 256), 256, 0, stream>>>(OS, x, gamma, out);
}

// Round 17
// 119.978 us; speedup vs baseline: 2.0893x; 2.0893x over previous
//
#include <hip/hip_runtime.h>
#include <hip/hip_bf16.h>

#define CCH 64      // channels
#define NPIX 4096   // 64*64 pooled points
#define LOG2E 1.4426950408889634f

typedef __attribute__((ext_vector_type(8))) short short8;   // 8 bf16 (4 VGPRs)
typedef __attribute__((ext_vector_type(16))) float f32x16;  // MFMA 32x32 accumulator

union U4S8 { uint4 u; short8 s; };

__device__ inline uint32_t pk2bf(float lo, float hi) {
    __hip_bfloat162 h = __float22bfloat162_rn(make_float2(lo, hi));
    return *reinterpret_cast<uint32_t*>(&h);
}

// ---------------------------------------------------------------------------
// Kernel 1: fused avg-pool 4x4 + 1x1 convs via MFMA. (unchanged from R13;
// Q pre-scaled by log2e). Measured ~27.7 us — near read floor.
// ---------------------------------------------------------------------------
__global__ __launch_bounds__(256, 4) void pool_conv_kernel(
    const float* __restrict__ x,
    const float* __restrict__ Wq, const float* __restrict__ bq,
    const float* __restrict__ Wk, const float* __restrict__ bk,
    const float* __restrict__ Wv, const float* __restrict__ bv,
    __hip_bfloat16* __restrict__ Qo, __hip_bfloat16* __restrict__ Ko,
    __hip_bfloat16* __restrict__ VPo)
{
    const int blk  = blockIdx.x;
    const int b    = blk >> 7;
    const int prow = (blk >> 1) & 63;    // pooled row
    const int half = blk & 1;            // pooled col half (32 cols)
    const int t    = threadIdx.x;
    const int lane = t & 63;
    const int w    = t >> 6;
    const int l31  = lane & 31;
    const int hi   = lane >> 5;

    __shared__ __align__(16) __hip_bfloat16 xdt[32][72];    // [pt][ch]
    __shared__ __align__(16) __hip_bfloat16 otile[80][36];  // [oc][pt]
    __shared__ float sbias[96];

    if (t < 96) {
        float v = 0.f;
        if (t < 8)       v = bq[t];
        else if (t < 16) v = bk[t-8];
        else if (t < 80) v = bv[t-16];
        sbias[t] = v;
    }

    const float* xbase = x + (((size_t)(b*CCH))*256 + (size_t)(prow*4 + hi))*256
                           + half*128 + l31*4;
    #pragma unroll
    for (int cc = 0; cc < 16; ++cc) {
        const int c = w*16 + cc;
        const float* xp = xbase + (size_t)c*65536;
        float4 a0 = *(const float4*)(xp);
        float4 a1 = *(const float4*)(xp + 512);    // +2 rows
        float s = (a0.x+a0.y+a0.z+a0.w) + (a1.x+a1.y+a1.z+a1.w);
        s += __shfl_xor(s, 32);                    // combine row pairs
        if (hi == 0) xdt[l31][c] = __float2bfloat16(s * 0.0625f);
    }

    const int  oct  = w;
    const bool busy = (w < 3);
    short8 wf[4];
    if (busy) {
        const int row = oct*32 + l31;
        const float* wr = nullptr;
        if (row < 8)       wr = Wq + row*CCH;
        else if (row < 16) wr = Wk + (row-8)*CCH;
        else if (row < 80) wr = Wv + (row-16)*CCH;
        #pragma unroll
        for (int kt = 0; kt < 4; ++kt) {
            U4S8 f;
            if (wr) {
                const int c0 = kt*16 + hi*8;
                float4 a = *(const float4*)(wr + c0);
                float4 d = *(const float4*)(wr + c0 + 4);
                f.u.x = pk2bf(a.x, a.y); f.u.y = pk2bf(a.z, a.w);
                f.u.z = pk2bf(d.x, d.y); f.u.w = pk2bf(d.z, d.w);
            } else {
                f.u = make_uint4(0,0,0,0);
            }
            wf[kt] = f.s;
        }
    }

    __syncthreads();

    if (busy) {
        short8 xf[4];
        #pragma unroll
        for (int kt = 0; kt < 4; ++kt)
            xf[kt] = *(const short8*)&xdt[l31][kt*16 + hi*8];

        f32x16 acc;
        #pragma unroll
        for (int r = 0; r < 16; ++r) acc[r] = 0.f;
        #pragma unroll
        for (int kt = 0; kt < 4; ++kt)
            acc = __builtin_amdgcn_mfma_f32_32x32x16_bf16(wf[kt], xf[kt], acc, 0, 0, 0);

        #pragma unroll
        for (int r = 0; r < 16; ++r) {
            const int row = (r&3) + 8*(r>>2) + 4*hi;
            const int oc  = oct*32 + row;
            if (oc < 80) {
                float v = acc[r] + sbias[oc];
                if (oc < 8) v *= LOG2E;   // Q pre-scale
                otile[oc][l31] = __float2bfloat16(v);
            }
        }
    }
    __syncthreads();

    const int i0 = prow*64 + half*32;
    if (t < 64) {
        const int p = t & 31;
        const int oc0 = (t < 32) ? 0 : 8;
        unsigned short v[8];
        #pragma unroll
        for (int j = 0; j < 8; ++j)
            v[j] = *reinterpret_cast<const unsigned short*>(&otile[oc0 + j][p]);
        uint4 q;
        q.x = (uint32_t)v[0] | ((uint32_t)v[1] << 16);
        q.y = (uint32_t)v[2] | ((uint32_t)v[3] << 16);
        q.z = (uint32_t)v[4] | ((uint32_t)v[5] << 16);
        q.w = (uint32_t)v[6] | ((uint32_t)v[7] << 16);
        __hip_bfloat16* dst = (t < 32) ? Qo : Ko;
        *(uint4*)(dst + ((size_t)b*NPIX + i0 + p)*8) = q;
    }
    {
        const int chg = i0 >> 5;
        __hip_bfloat16* vdst = VPo + ((size_t)b*512 + (size_t)chg*4)*512;
        const int f   = t >> 6;
        const int s1  = f >> 1;
        const int ct  = f & 1;
        const int l   = t & 63;
        const int c31 = l & 31;
        const int h2  = l >> 5;
        const int row = 16 + ct*32 + c31;
        const int pt0 = s1*16 + h2*4;
        uint2 a0 = *(const uint2*)&otile[row][pt0];         // j = 0..3
        uint2 a1 = *(const uint2*)&otile[row][pt0 + 8];     // j = 4..7
        *(uint4*)(vdst + t*8) = make_uint4(a0.x, a0.y, a1.x, a1.y);
    }
}

// ---------------------------------------------------------------------------
// Kernel 2: flash attention, software-pipelined, REGISTER BUDGET PINNED.
// R16 counters showed VGPR_Count=64: the compiler squeezed for 8 waves/EU
// (unreachable — LDS caps at 4 blocks/CU) and destroyed the prefetch
// (load-at-use => per-chunk L2 stalls; VALUBusy 79% was stall-filler).
// amdgpu_waves_per_eu(4,4) pins exactly 4 waves/EU => 128-VGPR budget;
// the ~116-reg live set fits, prefetch buffers stay live, latency hidden.
// ---------------------------------------------------------------------------
__attribute__((amdgpu_waves_per_eu(4, 4)))
__global__ __launch_bounds__(256) void attn_kernel(
    const __hip_bfloat16* __restrict__ Q, const __hip_bfloat16* __restrict__ K,
    const __hip_bfloat16* __restrict__ VP, float* __restrict__ OS)
{
    const int bb   = blockIdx.x;
    const int b    = bb & 7;          // XCD-locality: batch per XCD
    const int qg   = bb >> 3;         // 0..127
    const int i0   = qg * 32;
    const int t    = threadIdx.x;
    const int lane = t & 63;
    const int kvq  = t >> 6;          // wave = kv quarter
    const int l31  = lane & 31;
    const int hi   = lane >> 5;

    __shared__ float tiles[4][64][33];
    __shared__ float ml[4][32];
    __shared__ float ils[32];

    U4S8 qf;
    if (hi == 0) qf.u = *(const uint4*)(Q + ((size_t)b*NPIX + i0 + l31)*8);
    else         qf.u = make_uint4(0,0,0,0);

    const __hip_bfloat16* Kb  = K  + (size_t)b*NPIX*8;
    const __hip_bfloat16* VPb = VP + (size_t)b*512*512;   // 512 frags x 512 bf16

    f32x16 zacc;
    #pragma unroll
    for (int r = 0; r < 16; ++r) zacc[r] = 0.f;

    f32x16 acc0, acc1;
    #pragma unroll
    for (int r = 0; r < 16; ++r) { acc0[r] = 0.f; acc1[r] = 0.f; }
    float l0 = 0.f, l1 = 0.f, l2 = 0.f, l3 = 0.f;

    // per-chunk strides: K +256 elems (512B), VP +2048 elems (4KB)
    const __hip_bfloat16* Kp = Kb  + (size_t)(kvq*1024 + l31)*8;
    const __hip_bfloat16* Vp = VPb + (size_t)(kvq*32)*2048 + (size_t)lane*8;

    U4S8 kA, kB, vA0, vA1, vA2, vA3, vB0, vB1, vB2, vB3;
    // prologue: chunks 0,1 of this quarter
    if (hi == 0) kA.u = *(const uint4*)Kp; else kA.u = make_uint4(0,0,0,0);
    vA0.u = *(const uint4*)(Vp);
    vA1.u = *(const uint4*)(Vp + 512);
    vA2.u = *(const uint4*)(Vp + 1024);
    vA3.u = *(const uint4*)(Vp + 1536);
    Kp += 256; Vp += 2048;
    if (hi == 0) kB.u = *(const uint4*)Kp; else kB.u = make_uint4(0,0,0,0);
    vB0.u = *(const uint4*)(Vp);
    vB1.u = *(const uint4*)(Vp + 512);
    vB2.u = *(const uint4*)(Vp + 1024);
    vB3.u = *(const uint4*)(Vp + 1536);
    Kp += 256; Vp += 2048;

    #pragma unroll 1
    for (int it = 0; it < 16; ++it) {
        // ======== chunk 2*it (A buffers) ========
        {
            f32x16 s = __builtin_amdgcn_mfma_f32_32x32x16_bf16(kA.s, qf.s, zacc, 0, 0, 0);
            if (hi == 0) kA.u = *(const uint4*)Kp; else kA.u = make_uint4(0,0,0,0);
            Kp += 256;

            U4S8 pb0, pb1;
            float e0, e1;
            e0 = __builtin_exp2f(s[0]);  e1 = __builtin_exp2f(s[1]);
            l0 += e0 + e1;  pb0.u.x = pk2bf(e0, e1);
            e0 = __builtin_exp2f(s[2]);  e1 = __builtin_exp2f(s[3]);
            l1 += e0 + e1;  pb0.u.y = pk2bf(e0, e1);
            e0 = __builtin_exp2f(s[4]);  e1 = __builtin_exp2f(s[5]);
            l2 += e0 + e1;  pb0.u.z = pk2bf(e0, e1);
            e0 = __builtin_exp2f(s[6]);  e1 = __builtin_exp2f(s[7]);
            l3 += e0 + e1;  pb0.u.w = pk2bf(e0, e1);
            e0 = __builtin_exp2f(s[8]);  e1 = __builtin_exp2f(s[9]);
            l0 += e0 + e1;  pb1.u.x = pk2bf(e0, e1);
            e0 = __builtin_exp2f(s[10]); e1 = __builtin_exp2f(s[11]);
            l1 += e0 + e1;  pb1.u.y = pk2bf(e0, e1);
            e0 = __builtin_exp2f(s[12]); e1 = __builtin_exp2f(s[13]);
            l2 += e0 + e1;  pb1.u.z = pk2bf(e0, e1);
            e0 = __builtin_exp2f(s[14]); e1 = __builtin_exp2f(s[15]);
            l3 += e0 + e1;  pb1.u.w = pk2bf(e0, e1);

            acc0 = __builtin_amdgcn_mfma_f32_32x32x16_bf16(vA0.s, pb0.s, acc0, 0, 0, 0);
            acc1 = __builtin_amdgcn_mfma_f32_32x32x16_bf16(vA1.s, pb0.s, acc1, 0, 0, 0);
            acc0 = __builtin_amdgcn_mfma_f32_32x32x16_bf16(vA2.s, pb1.s, acc0, 0, 0, 0);
            acc1 = __builtin_amdgcn_mfma_f32_32x32x16_bf16(vA3.s, pb1.s, acc1, 0, 0, 0);
            vA0.u = *(const uint4*)(Vp);
            vA1.u = *(const uint4*)(Vp + 512);
            vA2.u = *(const uint4*)(Vp + 1024);
            vA3.u = *(const uint4*)(Vp + 1536);
            Vp += 2048;
        }
        // ======== chunk 2*it+1 (B buffers) ========
        {
            f32x16 s = __builtin_amdgcn_mfma_f32_32x32x16_bf16(kB.s, qf.s, zacc, 0, 0, 0);
            if (hi == 0) kB.u = *(const uint4*)Kp; else kB.u = make_uint4(0,0,0,0);
            Kp += 256;

            U4S8 pb0, pb1;
            float e0, e1;
            e0 = __builtin_exp2f(s[0]);  e1 = __builtin_exp2f(s[1]);
            l0 += e0 + e1;  pb0.u.x = pk2bf(e0, e1);
            e0 = __builtin_exp2f(s[2]);  e1 = __builtin_exp2f(s[3]);
            l1 += e0 + e1;  pb0.u.y = pk2bf(e0, e1);
            e0 = __builtin_exp2f(s[4]);  e1 = __builtin_exp2f(s[5]);
            l2 += e0 + e1;  pb0.u.z = pk2bf(e0, e1);
            e0 = __builtin_exp2f(s[6]);  e1 = __builtin_exp2f(s[7]);
            l3 += e0 + e1;  pb0.u.w = pk2bf(e0, e1);
            e0 = __builtin_exp2f(s[8]);  e1 = __builtin_exp2f(s[9]);
            l0 += e0 + e1;  pb1.u.x = pk2bf(e0, e1);
            e0 = __builtin_exp2f(s[10]); e1 = __builtin_exp2f(s[11]);
            l1 += e0 + e1;  pb1.u.y = pk2bf(e0, e1);
            e0 = __builtin_exp2f(s[12]); e1 = __builtin_exp2f(s[13]);
            l2 += e0 + e1;  pb1.u.z = pk2bf(e0, e1);
            e0 = __builtin_exp2f(s[14]); e1 = __builtin_exp2f(s[15]);
            l3 += e0 + e1;  pb1.u.w = pk2bf(e0, e1);

            acc0 = __builtin_amdgcn_mfma_f32_32x32x16_bf16(vB0.s, pb0.s, acc0, 0, 0, 0);
            acc1 = __builtin_amdgcn_mfma_f32_32x32x16_bf16(vB1.s, pb0.s, acc1, 0, 0, 0);
            acc0 = __builtin_amdgcn_mfma_f32_32x32x16_bf16(vB2.s, pb1.s, acc0, 0, 0, 0);
            acc1 = __builtin_amdgcn_mfma_f32_32x32x16_bf16(vB3.s, pb1.s, acc1, 0, 0, 0);
            vB0.u = *(const uint4*)(Vp);
            vB1.u = *(const uint4*)(Vp + 512);
            vB2.u = *(const uint4*)(Vp + 1024);
            vB3.u = *(const uint4*)(Vp + 1536);
            Vp += 2048;
        }
    }
    // (last-iteration prefetches read past the quarter: stays inside d_ws,
    // values unused — same as previous rounds.)

    float l = (l0 + l1) + (l2 + l3);
    l += __shfl_xor(l, 32);   // partner half holds other 16 kv per chunk

    #pragma unroll
    for (int r = 0; r < 16; ++r) {
        const int cr = (r&3) + 8*(r>>2) + 4*hi;
        tiles[kvq][cr]     [l31] = acc0[r];
        tiles[kvq][cr + 32][l31] = acc1[r];
    }
    if (hi == 0) ml[kvq][l31] = l;
    __syncthreads();

    if (t < 32) ils[t] = 1.f / (ml[0][t] + ml[1][t] + ml[2][t] + ml[3][t]);
    __syncthreads();

    float* outp = OS + (size_t)b*CCH*NPIX + i0;
    const int c  = t >> 2;
    const int q8 = (t & 3) * 8;
    float o[8];
    #pragma unroll
    for (int j = 0; j < 8; ++j) {
        const int q = q8 + j;
        float v = tiles[0][c][q] + tiles[1][c][q] + tiles[2][c][q] + tiles[3][c][q];
        o[j] = v * ils[q];
    }
    *(float4*)(outp + (size_t)c*NPIX + q8)     = make_float4(o[0], o[1], o[2], o[3]);
    *(float4*)(outp + (size_t)c*NPIX + q8 + 4) = make_float4(o[4], o[5], o[6], o[7]);
}

// ---------------------------------------------------------------------------
// Kernel 3: bilinear x4 upsample + residual (unchanged; measured ~42.7 us,
// at its memory floor).
// ---------------------------------------------------------------------------
__global__ __launch_bounds__(256) void upsample_add_kernel(
    const float* __restrict__ OS, const float* __restrict__ x,
    const float* __restrict__ gamma, float* __restrict__ out)
{
    const size_t qidx = (size_t)blockIdx.x * 256 + threadIdx.x;  // float4 index
    const size_t idx  = qidx * 4;
    const float g = gamma[0];
    const int w4 = (int)(idx & 255);
    const int h  = (int)((idx >> 8) & 255);
    const size_t bc = idx >> 16;

    const float scale = 63.0f / 255.0f;
    float fh = h * scale; int h0 = (int)fh; float fy = fh - (float)h0; int h1 = min(h0+1, 63);

    const float* r0 = OS + bc * (size_t)NPIX + h0*64;
    const float* r1 = OS + bc * (size_t)NPIX + h1*64;
    float4 xi = *(const float4*)(x + idx);

    float o[4];
    #pragma unroll
    for (int j = 0; j < 4; ++j) {
        const int w = w4 + j;
        float fw = w * scale; int w0 = (int)fw; float fx = fw - (float)w0; int w1 = min(w0+1, 63);
        float a0 = r0[w0], a1 = r0[w1], b0 = r1[w0], b1 = r1[w1];
        float vt = a0 + (a1 - a0) * fx;
        float vb = b0 + (b1 - b0) * fx;
        o[j] = vt + (vb - vt) * fy;
    }
    float4 ov;
    ov.x = g*o[0] + xi.x; ov.y = g*o[1] + xi.y;
    ov.z = g*o[2] + xi.z; ov.w = g*o[3] + xi.w;
    *(float4*)(out + idx) = ov;
}

// ---------------------------------------------------------------------------
extern "C" void kernel_launch(void* const* d_in, const int* in_sizes, int n_in,
                              void* d_out, int out_size, void* d_ws, size_t ws_size,
                              hipStream_t stream) {
    const float* x     = (const float*)d_in[0];
    const float* Wq    = (const float*)d_in[1];
    const float* bq    = (const float*)d_in[2];
    const float* Wk    = (const float*)d_in[3];
    const float* bk    = (const float*)d_in[4];
    const float* Wv    = (const float*)d_in[5];
    const float* bv    = (const float*)d_in[6];
    const float* gamma = (const float*)d_in[7];
    float* out = (float*)d_out;

    char* ws = (char*)d_ws;
    __hip_bfloat16* Qb = (__hip_bfloat16*)(ws);                      // 512 KB
    __hip_bfloat16* Kb = (__hip_bfloat16*)(ws + (size_t)( 512<<10)); // 512 KB
    __hip_bfloat16* VP = (__hip_bfloat16*)(ws + (size_t)(1024<<10)); // 4 MB packed
    float*          OS = (float*)         (ws + (size_t)(5120<<10)); // 8 MB

    pool_conv_kernel<<<1024, 256, 0, stream>>>(x, Wq, bq, Wk, bk, Wv, bv, Qb, Kb, VP);
    attn_kernel<<<1024, 256, 0, stream>>>(Qb, Kb, VP, OS);
    const size_t total4 = (size_t)8 * 64 * 256 * 256 / 4;
    upsample_add_kernel<<<(int)(total4 / 256), 256, 0, stream>>>(OS, x, gamma, out);
}